// Round 13
// baseline (279.166 us; speedup 1.0000x reference)
//
#include <hip/hip_runtime.h>
#include <cstddef>

#define B_ 32
#define C_ 32
#define L_ 16384
#define H_ 4
#define DH_ 8
#define NB_ 3
#define DOUT_ 10
#define SEG_ 512
#define S_ (L_/SEG_)   // 32 segments per (b,head)

#define TILE 256
#define AST  40    // A_lds row stride (halfs): 80 B/row; cols 32..39 = "holes" hold W1eff/W2

typedef _Float16 f16_t;
typedef _Float16 f16x2 __attribute__((ext_vector_type(2)));
typedef _Float16 f16x4 __attribute__((ext_vector_type(4)));
typedef _Float16 f16x8 __attribute__((ext_vector_type(8)));
typedef float    f32x4 __attribute__((ext_vector_type(4)));

// Branch-free gelu via Abramowitz-Stegun 7.1.25 erf approximation (|eps|<=2.5e-5,
// far below the f16 rounding the activation path already carries).
__device__ __forceinline__ float gelu_f(float x){
    const float z  = fabsf(x) * 0.70710678118654752440f;
    const float t  = __builtin_amdgcn_rcpf(fmaf(0.47047f, z, 1.0f));
    const float e  = __expf(-z * z);
    float p = fmaf(t, 0.7478556f, -0.0958798f);
    p = fmaf(t, p, 0.3480242f);
    const float erfz = 1.0f - p * t * e;          // erf(|x|/sqrt(2))
    const float phi  = fmaf(copysignf(erfz, x), 0.5f, 0.5f);
    return x * phi;
}

#define RED_MAX32(v) do{ v = fmaxf(v, __shfl_xor(v,1));  v = fmaxf(v, __shfl_xor(v,2)); \
                         v = fmaxf(v, __shfl_xor(v,4));  v = fmaxf(v, __shfl_xor(v,8)); \
                         v = fmaxf(v, __shfl_xor(v,16)); }while(0)
#define RED_SUM32(v) do{ v += __shfl_xor(v,1);  v += __shfl_xor(v,2); \
                         v += __shfl_xor(v,4);  v += __shfl_xor(v,8); \
                         v += __shfl_xor(v,16); }while(0)

// ---- stats: per (b, head, seg) partial max / sumexp / kv over a 512-pos segment ----
// f32 for x (layer 0), f16 for hbuf (layers 1,2 -- 32 MB, L3-resident).
// x16: layer 0 also emits the f16 conversion of x into hbuf while streaming
// (pure-BW writes; removes 32 MB of reads from the latency-bound block0, which
// then runs in-place on hbuf exactly like block1). R11 counters: this saved ~11 us.
// zpool: one WG zeroes pooled (replaces the memset launch).
template<typename T>
__global__ __launch_bounds__(256) void stats_kernel(const T* __restrict__ h,
                                                    float* __restrict__ part,
                                                    float* __restrict__ zpool,
                                                    f16_t* __restrict__ x16){
    const int seg = blockIdx.x;
    const int hd  = blockIdx.y;
    const int b   = blockIdx.z;
    const int t   = threadIdx.x;
    const int d   = t >> 5;   // 0..7  (feature within head); wave-half owns one d
    const int j   = t & 31;   // 0..31 (position lane)

    __shared__ float tile[8][SEG_];   // 16 KB
    __shared__ float sm[8];

    if (zpool != nullptr && blockIdx.x == 0 && blockIdx.y == 0 && blockIdx.z == 0)
        for (int i = t; i < B_*C_; i += 256) zpool[i] = 0.0f;

    const size_t boff = (size_t)b * ((size_t)C_*L_) + (size_t)(hd*DH_)*L_ + (size_t)seg*SEG_;
    const T* hb = h + boff;

    if constexpr (sizeof(T) == 4){
        f16_t* xb = (x16 != nullptr) ? (x16 + boff) : nullptr;
        for (int f = t; f < 8*SEG_/4; f += 256){
            const int row = f >> 7;
            const int c4  = (f & 127) << 2;
            const f32x4 v = *(const f32x4*)&hb[(size_t)row*L_ + c4];
            *(f32x4*)&tile[row][c4] = v;
            if (xb != nullptr){
                f16x4 hv = { (f16_t)v[0], (f16_t)v[1], (f16_t)v[2], (f16_t)v[3] };
                *(f16x4*)&xb[(size_t)row*L_ + c4] = hv;
            }
        }
    } else {
        for (int f = t; f < 8*SEG_/8; f += 256){
            const int row = f >> 6;            // 64 f16x8 chunks per row
            const int c8  = (f & 63) << 3;
            const f16x8 v = *(const f16x8*)&hb[(size_t)row*L_ + c8];
            f32x4 lo = {(float)v[0], (float)v[1], (float)v[2], (float)v[3]};
            f32x4 hi = {(float)v[4], (float)v[5], (float)v[6], (float)v[7]};
            *(f32x4*)&tile[row][c8]     = lo;
            *(f32x4*)&tile[row][c8 + 4] = hi;
        }
    }
    __syncthreads();

    float m = -INFINITY;
    #pragma unroll
    for (int i = 0; i < SEG_/32; i++) m = fmaxf(m, tile[d][j + 32*i]);
    RED_MAX32(m);
    if (j == 0) sm[d] = m;
    const float m_d = m;

    float s = 0.0f;
    float kv[8];
    #pragma unroll
    for (int e = 0; e < 8; e++) kv[e] = 0.0f;
    #pragma unroll
    for (int i = 0; i < SEG_/32; i++){
        const int k = j + 32*i;
        const float ek = __expf(tile[d][k] - m_d);
        s += ek;
        #pragma unroll
        for (int e = 0; e < 8; e++) kv[e] = fmaf(ek, tile[e][k], kv[e]);
    }
    RED_SUM32(s);
    #pragma unroll
    for (int e = 0; e < 8; e++){ RED_SUM32(kv[e]); }
    __syncthreads();

    float* po = part + (size_t)((b*H_ + hd)*S_ + seg) * 80;
    if (j == 0){
        po[8 + d] = s;
        #pragma unroll
        for (int e = 0; e < 8; e++) po[16 + d*8 + e] = kv[e];
    }
    if (t < 8) po[t] = sm[t];
}

// ---- per-position softmax P + FC1/FC2 via f16 MFMA (R10 structure) ----
//  * REGISTER-DIRECT A-FRAGS: lane (lk,lr) of wave wv owns head lk for the 4
//    positions wv*64+mt*16+lr; softmax lane-local; P IS the MFMA A-fragment.
//  * WEIGHTS IN AO HOLES: AST=40 leaves 8 halfs/row; W1eff hole-rows 0..127,
//    W2 hole-rows 128..255. LDS = 20480 B exactly -> 8 WG/CU, single round.
//  * SHUFFLE-COMBINE MERGE: 4 segments/lane + 3-step shfl_xor logsumexp ->
//    full kvn row in registers; ONE __syncthreads total.
//  * In-place hbuf I/O (f16): each WG reads exactly the positions it writes,
//    reads in prologue / writes in epilogue -> safe.
//  * LAST: pooling via shfl + plain global atomicAdd. NO __threadfence (R11:
//    device-scope fences = L2 writeback storm on non-coherent-XCD CDNA4,
//    +130 us). Kernel boundary = ordering.
// OCCUPANCY (R12 post-mortem): with the live set down to 52 VGPRs, the old
// waves_per_eu(3,4) attr became the binding constraint -- occupancy pinned at
// ~35% across rounds while LDS/VGPR allowed 8 WG/CU. (6,8): min=6 caps regs at
// 85 >= 52 natural (no contraction-spill, unlike R1 where natural was ~75),
// max=8 lifts the envelope to the LDS limit. Spill check: WRITE_SIZE must stay
// ~32.8 MB (block0/1).
// MFMA layouts (m89/m91-verified): A-frag lane holds A[m=lane&15][k=(lane>>4)*8+j];
// B-frag B[k][n=lane&15]; C/D col=lane&15, row=(lane>>4)*4+reg.
template<bool LAST>
__global__ __launch_bounds__(256)
__attribute__((amdgpu_waves_per_eu(6, 8)))
void block_kernel(const f16_t* hin,
                  f16_t* hout,
                  const float* __restrict__ part,
                  const float* __restrict__ W1,
                  const float* __restrict__ b1,
                  const float* __restrict__ W2,
                  const float* __restrict__ b2,
                  float* __restrict__ pooled){
    __shared__ __align__(16) f16_t AO[TILE*AST];   // 20480 B total LDS

    const int tid  = threadIdx.x;
    const int b    = blockIdx.y;
    const int l0   = blockIdx.x * TILE;
    const size_t base = (size_t)b * ((size_t)C_*L_);

    const int wv   = tid >> 6;
    const int lane = tid & 63;
    const int lr   = lane & 15;
    const int lk   = lane >> 4;
    const int posb = l0 + wv*64 + lr;   // + mt*16

    // ---- prologue: h loads (reg-direct A layout), W2 -> holes, biases ----
    float h[4][8];
    #pragma unroll
    for (int j = 0; j < 8; j++)
        #pragma unroll
        for (int mt = 0; mt < 4; mt++)
            h[mt][j] = (float)hin[base + (size_t)(lk*8 + j)*L_ + posb + mt*16];

    // W2 -> hole-rows 128..255: W2[k*32+n] -> hole(n,k)
    for (int i = tid; i < 1024; i += 256){
        const int k = i >> 5, n = i & 31;
        AO[(size_t)(128 + n*4 + (k >> 3))*AST + 32 + (k & 7)] = (f16_t)W2[i];
    }
    float bias1[2], bias2[2];
    #pragma unroll
    for (int nt = 0; nt < 2; nt++){ bias1[nt] = b1[nt*16 + lr]; bias2[nt] = b2[nt*16 + lr]; }

    // ---- per-position softmax -> A-frags in registers (h dies here) ----
    f16x8 a[4];
    #pragma unroll
    for (int mt = 0; mt < 4; mt++){
        float mq = h[mt][0];
        #pragma unroll
        for (int j = 1; j < 8; j++) mq = fmaxf(mq, h[mt][j]);
        float es[8]; float qs = 0.f;
        #pragma unroll
        for (int j = 0; j < 8; j++){ es[j] = __expf(h[mt][j] - mq); qs += es[j]; }
        const float inv = __builtin_amdgcn_rcpf(qs);
        #pragma unroll
        for (int j = 0; j < 8; j++) a[mt][j] = (f16_t)(es[j] * inv);
    }

    // ---- merge: 4 segments per lane + shfl logsumexp combine over 8 q-lanes ----
    const int row = tid >> 3;        // c_in 0..31
    const int qq  = tid & 7;         // segment group / n-column group
    const int hdm = row >> 3, dm = row & 7;
    {
        const float* pp = part + (size_t)(b*H_ + hdm) * S_ * 80;
        float pm[4];
        #pragma unroll
        for (int t4 = 0; t4 < 4; t4++) pm[t4] = pp[(qq + 8*t4)*80 + dm];
        float M = fmaxf(fmaxf(pm[0], pm[1]), fmaxf(pm[2], pm[3]));
        float ss = 0.f;
        float kvr[8];
        #pragma unroll
        for (int e = 0; e < 8; e++) kvr[e] = 0.f;
        #pragma unroll
        for (int t4 = 0; t4 < 4; t4++){
            const int s = qq + 8*t4;
            const float sc = __expf(pm[t4] - M);
            ss = fmaf(pp[s*80 + 8 + dm], sc, ss);
            const f32x4 k0 = *(const f32x4*)&pp[s*80 + 16 + dm*8];
            const f32x4 k1 = *(const f32x4*)&pp[s*80 + 16 + dm*8 + 4];
            #pragma unroll
            for (int e = 0; e < 4; e++){
                kvr[e]   = fmaf(k0[e], sc, kvr[e]);
                kvr[4+e] = fmaf(k1[e], sc, kvr[4+e]);
            }
        }
        // combine across the 8 q-lanes (lane bits 0..2): logsumexp merge
        #pragma unroll
        for (int off = 1; off < 8; off <<= 1){
            const float Mo  = __shfl_xor(M, off);
            const float sso = __shfl_xor(ss, off);
            const float Mn  = fmaxf(M, Mo);
            const float sa  = __expf(M - Mn), sb = __expf(Mo - Mn);
            ss = ss*sa + sso*sb;
            #pragma unroll
            for (int e = 0; e < 8; e++){
                const float ko = __shfl_xor(kvr[e], off);
                kvr[e] = kvr[e]*sa + ko*sb;
            }
            M = Mn;
        }
        const float iss = 1.0f / ss;

        // W1eff[row][qq*4..+3] = sum_e kvn[row][e] * W1[hdm*8+e][qq*4..+3] -> holes 0..127
        f32x4 acc = {0.f, 0.f, 0.f, 0.f};
        #pragma unroll
        for (int e = 0; e < 8; e++){
            const f32x4 w = *(const f32x4*)&W1[(hdm*8 + e)*32 + qq*4];
            acc += kvr[e] * w;
        }
        #pragma unroll
        for (int j2 = 0; j2 < 4; j2++)
            AO[(size_t)((qq*4 + j2)*4 + hdm)*AST + 32 + dm] = (f16_t)(acc[j2] * iss);
    }
    __syncthreads();   // the ONLY barrier: W1eff + W2 holes visible

    // ---- MFMA FCs ----
    const f32x4 zero = {0.f, 0.f, 0.f, 0.f};
    f16x8 bw[2];
    f32x4 d[8];

    // FC1: A = P (registers), B = W1eff (holes 0..127)
    #pragma unroll
    for (int nt = 0; nt < 2; nt++)
        bw[nt] = *(const f16x8*)&AO[(size_t)((nt*16 + lr)*4 + lk)*AST + 32];
    #pragma unroll
    for (int nt = 0; nt < 2; nt++)
        #pragma unroll
        for (int mt = 0; mt < 4; mt++)
            d[nt*4+mt] = __builtin_amdgcn_mfma_f32_16x16x32_f16(a[mt], bw[nt], zero, 0, 0, 0);

    // bias + gelu + writeback as A2 into AO rows (cols 0..31; wave-private rows)
    #pragma unroll
    for (int nt = 0; nt < 2; nt++){
        #pragma unroll
        for (int mt = 0; mt < 4; mt++)
            #pragma unroll
            for (int r = 0; r < 4; r++){
                const float v = gelu_f(d[nt*4+mt][r] + bias1[nt]);
                AO[(size_t)(wv*64 + mt*16 + lk*4 + r)*AST + (nt*16 + lr)] = (f16_t)v;
            }
    }

    // FC2: A2 from AO rows, B = W2 (holes 128..255). Same-wave LDS write->read
    // ordering (R5-verified) -- no barrier.
    f16x8 a2[4];
    #pragma unroll
    for (int mt = 0; mt < 4; mt++)
        a2[mt] = *(const f16x8*)&AO[(size_t)(wv*64 + mt*16 + lr)*AST + lk*8];
    #pragma unroll
    for (int nt = 0; nt < 2; nt++)
        bw[nt] = *(const f16x8*)&AO[(size_t)(128 + (nt*16 + lr)*4 + lk)*AST + 32];
    #pragma unroll
    for (int nt = 0; nt < 2; nt++)
        #pragma unroll
        for (int mt = 0; mt < 4; mt++)
            d[nt*4+mt] = __builtin_amdgcn_mfma_f32_16x16x32_f16(a2[mt], bw[nt], zero, 0, 0, 0);

    // bias + gelu on D (fp32)
    #pragma unroll
    for (int nt = 0; nt < 2; nt++)
        #pragma unroll
        for (int mt = 0; mt < 4; mt++)
            #pragma unroll
            for (int r = 0; r < 4; r++)
                d[nt*4+mt][r] = gelu_f(d[nt*4+mt][r] + bias2[nt]);

    if (!LAST){
        // direct f16x4 store: lane owns 4 consecutive positions of channel nt*16+lr
        #pragma unroll
        for (int nt = 0; nt < 2; nt++)
            #pragma unroll
            for (int mt = 0; mt < 4; mt++){
                const f32x4 dv = d[nt*4+mt];
                f16x4 hv = { (f16_t)dv[0], (f16_t)dv[1], (f16_t)dv[2], (f16_t)dv[3] };
                *(f16x4*)&hout[base + (size_t)(nt*16 + lr)*L_
                               + l0 + wv*64 + mt*16 + lk*4] = hv;
            }
    } else {
        // channel sums: reduce over the 4 lk-lanes sharing lr, then global atomic.
        // No fence: the head_kernel launch boundary orders pooled visibility.
        #pragma unroll
        for (int nt = 0; nt < 2; nt++){
            float ps = 0.f;
            #pragma unroll
            for (int mt = 0; mt < 4; mt++)
                ps += d[nt*4+mt][0] + d[nt*4+mt][1] + d[nt*4+mt][2] + d[nt*4+mt][3];
            ps += __shfl_xor(ps, 16);
            ps += __shfl_xor(ps, 32);
            if (lk == 0) atomicAdd(&pooled[b*32 + nt*16 + lr], ps);
        }
    }
}

// ---- head: pooled/L -> Wh+bh -> BN(eval) -> gelu -> Wf+bf ----
__global__ __launch_bounds__(1024) void head_kernel(const float* __restrict__ pooled,
                                                    const float* __restrict__ Wh,
                                                    const float* __restrict__ bh,
                                                    const float* __restrict__ gam,
                                                    const float* __restrict__ bet,
                                                    const float* __restrict__ mean,
                                                    const float* __restrict__ var,
                                                    const float* __restrict__ Wf,
                                                    const float* __restrict__ bf,
                                                    float* __restrict__ out){
    __shared__ float y2[32][32];
    const int t = threadIdx.x;      // 0..1023
    const int b = t >> 5, c = t & 31;
    float a = bh[c];
    const float invL = 1.0f / (float)L_;
    #pragma unroll
    for (int d = 0; d < 32; d++) a += (pooled[b*32 + d] * invL) * Wh[d*32 + c];
    a = (a - mean[c]) * rsqrtf(var[c] + 1e-5f) * gam[c] + bet[c];
    y2[b][c] = gelu_f(a);
    __syncthreads();
    if (t < B_*DOUT_){
        const int b2 = t / DOUT_, j = t % DOUT_;
        float r = bf[j];
        #pragma unroll
        for (int c2 = 0; c2 < 32; c2++) r += y2[b2][c2] * Wf[c2*DOUT_ + j];
        out[t] = r;
    }
}

extern "C" void kernel_launch(void* const* d_in, const int* in_sizes, int n_in,
                              void* d_out, int out_size, void* d_ws, size_t ws_size,
                              hipStream_t stream){
    (void)in_sizes; (void)n_in; (void)out_size; (void)ws_size;
    const float* x    = (const float*)d_in[0];
    const float* fW1  = (const float*)d_in[1];
    const float* fb1  = (const float*)d_in[2];
    const float* fW2  = (const float*)d_in[3];
    const float* fb2  = (const float*)d_in[4];
    const float* Wh   = (const float*)d_in[5];
    const float* bh   = (const float*)d_in[6];
    const float* gam  = (const float*)d_in[7];
    const float* bet  = (const float*)d_in[8];
    const float* mean = (const float*)d_in[9];
    const float* var  = (const float*)d_in[10];
    const float* Wf   = (const float*)d_in[11];
    const float* bf   = (const float*)d_in[12];
    float* out = (float*)d_out;

    f16_t* hbuf   = (f16_t*)d_ws;                                  // B*C*L f16 (32 MB)
    float* part   = (float*)((char*)d_ws + (size_t)B_*C_*L_*2);    // B*H*S_*80 (~1.3 MB)
    float* pooled = part + (size_t)B_*H_*S_*80;                    // B*C

    dim3 sgrid(S_, H_, B_);
    dim3 bgrid(L_/TILE, B_);

    // 7 dispatches (x16 fused into stats0; pooled-zero fused into stats2;
    // head separate -- kernel boundary is the cheap ordering primitive).
    // stats0: reads x f32, writes part + x16 -> hbuf
    stats_kernel<float><<<sgrid, 256, 0, stream>>>(x, part, nullptr, hbuf);
    // block 0: in-place on hbuf f16
    block_kernel<false><<<bgrid, 256, 0, stream>>>(hbuf, hbuf, part,
        fW1, fb1, fW2, fb2, nullptr);
    // block 1 (in-place on hbuf f16)
    stats_kernel<f16_t><<<sgrid, 256, 0, stream>>>(hbuf, part, nullptr, nullptr);
    block_kernel<false><<<bgrid, 256, 0, stream>>>(hbuf, hbuf, part,
        fW1 + C_*C_, fb1 + C_, fW2 + C_*C_, fb2 + C_, nullptr);
    // block 2 (no h write; pooled reduce; stats2 zeroes pooled)
    stats_kernel<f16_t><<<sgrid, 256, 0, stream>>>(hbuf, part, pooled, nullptr);
    block_kernel<true><<<bgrid, 256, 0, stream>>>(hbuf, nullptr, part,
        fW1 + 2*C_*C_, fb1 + 2*C_, fW2 + 2*C_*C_, fb2 + 2*C_, pooled);

    head_kernel<<<1, 1024, 0, stream>>>(pooled, Wh, bh, gam, bet, mean, var, Wf, bf, out);
}

// Round 14
// 275.872 us; speedup vs baseline: 1.0119x; 1.0119x over previous
//
#include <hip/hip_runtime.h>
#include <cstddef>

#define B_ 32
#define C_ 32
#define L_ 16384
#define H_ 4
#define DH_ 8
#define NB_ 3
#define DOUT_ 10
#define SEG_ 512
#define S_ (L_/SEG_)   // 32 segments per (b,head)

#define TILE 256
#define AST  40    // A_lds row stride (halfs): 80 B/row; cols 32..39 = "holes" hold W1eff/W2

typedef _Float16 f16_t;
typedef _Float16 f16x2 __attribute__((ext_vector_type(2)));
typedef _Float16 f16x4 __attribute__((ext_vector_type(4)));
typedef _Float16 f16x8 __attribute__((ext_vector_type(8)));
typedef float    f32x4 __attribute__((ext_vector_type(4)));

// Branch-free gelu via Abramowitz-Stegun 7.1.25 erf approximation (|eps|<=2.5e-5,
// far below the f16 rounding the activation path already carries).
__device__ __forceinline__ float gelu_f(float x){
    const float z  = fabsf(x) * 0.70710678118654752440f;
    const float t  = __builtin_amdgcn_rcpf(fmaf(0.47047f, z, 1.0f));
    const float e  = __expf(-z * z);
    float p = fmaf(t, 0.7478556f, -0.0958798f);
    p = fmaf(t, p, 0.3480242f);
    const float erfz = 1.0f - p * t * e;          // erf(|x|/sqrt(2))
    const float phi  = fmaf(copysignf(erfz, x), 0.5f, 0.5f);
    return x * phi;
}

#define RED_MAX32(v) do{ v = fmaxf(v, __shfl_xor(v,1));  v = fmaxf(v, __shfl_xor(v,2)); \
                         v = fmaxf(v, __shfl_xor(v,4));  v = fmaxf(v, __shfl_xor(v,8)); \
                         v = fmaxf(v, __shfl_xor(v,16)); }while(0)
#define RED_SUM32(v) do{ v += __shfl_xor(v,1);  v += __shfl_xor(v,2); \
                         v += __shfl_xor(v,4);  v += __shfl_xor(v,8); \
                         v += __shfl_xor(v,16); }while(0)

// ---- stats: per (b, head, seg) partial max / sumexp / kv over a 512-pos segment ----
// f32 for x (layer 0), f16 for hbuf (layers 1,2 -- 32 MB, L3-resident).
// x16: layer 0 also emits the f16 conversion of x into hbuf while streaming
// (pure-BW writes; removes 32 MB of reads from the latency-bound block0, which
// then runs in-place on hbuf exactly like block1). R11 counters: this saved ~11 us.
// zpool: one WG zeroes pooled (replaces the memset launch).
template<typename T>
__global__ __launch_bounds__(256) void stats_kernel(const T* __restrict__ h,
                                                    float* __restrict__ part,
                                                    float* __restrict__ zpool,
                                                    f16_t* __restrict__ x16){
    const int seg = blockIdx.x;
    const int hd  = blockIdx.y;
    const int b   = blockIdx.z;
    const int t   = threadIdx.x;
    const int d   = t >> 5;   // 0..7  (feature within head); wave-half owns one d
    const int j   = t & 31;   // 0..31 (position lane)

    __shared__ float tile[8][SEG_];   // 16 KB
    __shared__ float sm[8];

    if (zpool != nullptr && blockIdx.x == 0 && blockIdx.y == 0 && blockIdx.z == 0)
        for (int i = t; i < B_*C_; i += 256) zpool[i] = 0.0f;

    const size_t boff = (size_t)b * ((size_t)C_*L_) + (size_t)(hd*DH_)*L_ + (size_t)seg*SEG_;
    const T* hb = h + boff;

    if constexpr (sizeof(T) == 4){
        f16_t* xb = (x16 != nullptr) ? (x16 + boff) : nullptr;
        for (int f = t; f < 8*SEG_/4; f += 256){
            const int row = f >> 7;
            const int c4  = (f & 127) << 2;
            const f32x4 v = *(const f32x4*)&hb[(size_t)row*L_ + c4];
            *(f32x4*)&tile[row][c4] = v;
            if (xb != nullptr){
                f16x4 hv = { (f16_t)v[0], (f16_t)v[1], (f16_t)v[2], (f16_t)v[3] };
                *(f16x4*)&xb[(size_t)row*L_ + c4] = hv;
            }
        }
    } else {
        for (int f = t; f < 8*SEG_/8; f += 256){
            const int row = f >> 6;            // 64 f16x8 chunks per row
            const int c8  = (f & 63) << 3;
            const f16x8 v = *(const f16x8*)&hb[(size_t)row*L_ + c8];
            f32x4 lo = {(float)v[0], (float)v[1], (float)v[2], (float)v[3]};
            f32x4 hi = {(float)v[4], (float)v[5], (float)v[6], (float)v[7]};
            *(f32x4*)&tile[row][c8]     = lo;
            *(f32x4*)&tile[row][c8 + 4] = hi;
        }
    }
    __syncthreads();

    float m = -INFINITY;
    #pragma unroll
    for (int i = 0; i < SEG_/32; i++) m = fmaxf(m, tile[d][j + 32*i]);
    RED_MAX32(m);
    if (j == 0) sm[d] = m;
    const float m_d = m;

    float s = 0.0f;
    float kv[8];
    #pragma unroll
    for (int e = 0; e < 8; e++) kv[e] = 0.0f;
    #pragma unroll
    for (int i = 0; i < SEG_/32; i++){
        const int k = j + 32*i;
        const float ek = __expf(tile[d][k] - m_d);
        s += ek;
        #pragma unroll
        for (int e = 0; e < 8; e++) kv[e] = fmaf(ek, tile[e][k], kv[e]);
    }
    RED_SUM32(s);
    #pragma unroll
    for (int e = 0; e < 8; e++){ RED_SUM32(kv[e]); }
    __syncthreads();

    float* po = part + (size_t)((b*H_ + hd)*S_ + seg) * 80;
    if (j == 0){
        po[8 + d] = s;
        #pragma unroll
        for (int e = 0; e < 8; e++) po[16 + d*8 + e] = kv[e];
    }
    if (t < 8) po[t] = sm[t];
}

// ---- per-position softmax P + FC1/FC2 via f16 MFMA (R10 structure) ----
//  * REGISTER-DIRECT A-FRAGS: lane (lk,lr) of wave wv owns head lk for the 4
//    positions wv*64+mt*16+lr; softmax lane-local; P IS the MFMA A-fragment.
//  * WEIGHTS IN AO HOLES: AST=40 leaves 8 halfs/row; W1eff hole-rows 0..127,
//    W2 hole-rows 128..255. LDS = 20480 B exactly -> 8 WG/CU, single round.
//  * SHUFFLE-COMBINE MERGE: 4 segments/lane + 3-step shfl_xor logsumexp ->
//    full kvn row in registers; ONE __syncthreads total.
//  * In-place hbuf I/O (f16). LAST: shfl + plain atomicAdd, NO fences (R11:
//    device-scope fences = L2 writeback storm on non-coherent-XCD CDNA4).
// OCCUPANCY LADDER (R12/R13 post-mortems):
//   (3,4): VGPR 52, no spill, occ 35%, blocks ~50 us  -> max=4 envelope binds.
//   (6,8): VGPR 40 = CONTRACTION SPILL (~6 MB/dispatch), occ 40%, blocks ~40 us
//          -> envelope lift is worth ~10 us/block, but min>=5 always contracts.
//   (4,8): min=4 -> reg cap 128 >= 52 natural (no contraction; same mechanism
//          that kept (3,4) spill-free), max=8 keeps the envelope at the LDS
//          limit. Spill check: WRITE_SIZE must be ~32.8 MB (block0/1) / ~1 MB (LAST).
// MFMA layouts (m89/m91-verified): A-frag lane holds A[m=lane&15][k=(lane>>4)*8+j];
// B-frag B[k][n=lane&15]; C/D col=lane&15, row=(lane>>4)*4+reg.
template<bool LAST>
__global__ __launch_bounds__(256)
__attribute__((amdgpu_waves_per_eu(4, 8)))
void block_kernel(const f16_t* hin,
                  f16_t* hout,
                  const float* __restrict__ part,
                  const float* __restrict__ W1,
                  const float* __restrict__ b1,
                  const float* __restrict__ W2,
                  const float* __restrict__ b2,
                  float* __restrict__ pooled){
    __shared__ __align__(16) f16_t AO[TILE*AST];   // 20480 B total LDS

    const int tid  = threadIdx.x;
    const int b    = blockIdx.y;
    const int l0   = blockIdx.x * TILE;
    const size_t base = (size_t)b * ((size_t)C_*L_);

    const int wv   = tid >> 6;
    const int lane = tid & 63;
    const int lr   = lane & 15;
    const int lk   = lane >> 4;
    const int posb = l0 + wv*64 + lr;   // + mt*16

    // ---- prologue: h loads (reg-direct A layout), W2 -> holes, biases ----
    float h[4][8];
    #pragma unroll
    for (int j = 0; j < 8; j++)
        #pragma unroll
        for (int mt = 0; mt < 4; mt++)
            h[mt][j] = (float)hin[base + (size_t)(lk*8 + j)*L_ + posb + mt*16];

    // W2 -> hole-rows 128..255: W2[k*32+n] -> hole(n,k)
    for (int i = tid; i < 1024; i += 256){
        const int k = i >> 5, n = i & 31;
        AO[(size_t)(128 + n*4 + (k >> 3))*AST + 32 + (k & 7)] = (f16_t)W2[i];
    }
    float bias1[2], bias2[2];
    #pragma unroll
    for (int nt = 0; nt < 2; nt++){ bias1[nt] = b1[nt*16 + lr]; bias2[nt] = b2[nt*16 + lr]; }

    // ---- per-position softmax -> A-frags in registers (h dies here) ----
    f16x8 a[4];
    #pragma unroll
    for (int mt = 0; mt < 4; mt++){
        float mq = h[mt][0];
        #pragma unroll
        for (int j = 1; j < 8; j++) mq = fmaxf(mq, h[mt][j]);
        float es[8]; float qs = 0.f;
        #pragma unroll
        for (int j = 0; j < 8; j++){ es[j] = __expf(h[mt][j] - mq); qs += es[j]; }
        const float inv = __builtin_amdgcn_rcpf(qs);
        #pragma unroll
        for (int j = 0; j < 8; j++) a[mt][j] = (f16_t)(es[j] * inv);
    }

    // ---- merge: 4 segments per lane + shfl logsumexp combine over 8 q-lanes ----
    const int row = tid >> 3;        // c_in 0..31
    const int qq  = tid & 7;         // segment group / n-column group
    const int hdm = row >> 3, dm = row & 7;
    {
        const float* pp = part + (size_t)(b*H_ + hdm) * S_ * 80;
        float pm[4];
        #pragma unroll
        for (int t4 = 0; t4 < 4; t4++) pm[t4] = pp[(qq + 8*t4)*80 + dm];
        float M = fmaxf(fmaxf(pm[0], pm[1]), fmaxf(pm[2], pm[3]));
        float ss = 0.f;
        float kvr[8];
        #pragma unroll
        for (int e = 0; e < 8; e++) kvr[e] = 0.f;
        #pragma unroll
        for (int t4 = 0; t4 < 4; t4++){
            const int s = qq + 8*t4;
            const float sc = __expf(pm[t4] - M);
            ss = fmaf(pp[s*80 + 8 + dm], sc, ss);
            const f32x4 k0 = *(const f32x4*)&pp[s*80 + 16 + dm*8];
            const f32x4 k1 = *(const f32x4*)&pp[s*80 + 16 + dm*8 + 4];
            #pragma unroll
            for (int e = 0; e < 4; e++){
                kvr[e]   = fmaf(k0[e], sc, kvr[e]);
                kvr[4+e] = fmaf(k1[e], sc, kvr[4+e]);
            }
        }
        // combine across the 8 q-lanes (lane bits 0..2): logsumexp merge
        #pragma unroll
        for (int off = 1; off < 8; off <<= 1){
            const float Mo  = __shfl_xor(M, off);
            const float sso = __shfl_xor(ss, off);
            const float Mn  = fmaxf(M, Mo);
            const float sa  = __expf(M - Mn), sb = __expf(Mo - Mn);
            ss = ss*sa + sso*sb;
            #pragma unroll
            for (int e = 0; e < 8; e++){
                const float ko = __shfl_xor(kvr[e], off);
                kvr[e] = kvr[e]*sa + ko*sb;
            }
            M = Mn;
        }
        const float iss = 1.0f / ss;

        // W1eff[row][qq*4..+3] = sum_e kvn[row][e] * W1[hdm*8+e][qq*4..+3] -> holes 0..127
        f32x4 acc = {0.f, 0.f, 0.f, 0.f};
        #pragma unroll
        for (int e = 0; e < 8; e++){
            const f32x4 w = *(const f32x4*)&W1[(hdm*8 + e)*32 + qq*4];
            acc += kvr[e] * w;
        }
        #pragma unroll
        for (int j2 = 0; j2 < 4; j2++)
            AO[(size_t)((qq*4 + j2)*4 + hdm)*AST + 32 + dm] = (f16_t)(acc[j2] * iss);
    }
    __syncthreads();   // the ONLY barrier: W1eff + W2 holes visible

    // ---- MFMA FCs ----
    const f32x4 zero = {0.f, 0.f, 0.f, 0.f};
    f16x8 bw[2];
    f32x4 d[8];

    // FC1: A = P (registers), B = W1eff (holes 0..127)
    #pragma unroll
    for (int nt = 0; nt < 2; nt++)
        bw[nt] = *(const f16x8*)&AO[(size_t)((nt*16 + lr)*4 + lk)*AST + 32];
    #pragma unroll
    for (int nt = 0; nt < 2; nt++)
        #pragma unroll
        for (int mt = 0; mt < 4; mt++)
            d[nt*4+mt] = __builtin_amdgcn_mfma_f32_16x16x32_f16(a[mt], bw[nt], zero, 0, 0, 0);

    // bias + gelu + writeback as A2 into AO rows (cols 0..31; wave-private rows)
    #pragma unroll
    for (int nt = 0; nt < 2; nt++){
        #pragma unroll
        for (int mt = 0; mt < 4; mt++)
            #pragma unroll
            for (int r = 0; r < 4; r++){
                const float v = gelu_f(d[nt*4+mt][r] + bias1[nt]);
                AO[(size_t)(wv*64 + mt*16 + lk*4 + r)*AST + (nt*16 + lr)] = (f16_t)v;
            }
    }

    // FC2: A2 from AO rows, B = W2 (holes 128..255). Same-wave LDS write->read
    // ordering (R5-verified) -- no barrier.
    f16x8 a2[4];
    #pragma unroll
    for (int mt = 0; mt < 4; mt++)
        a2[mt] = *(const f16x8*)&AO[(size_t)(wv*64 + mt*16 + lr)*AST + lk*8];
    #pragma unroll
    for (int nt = 0; nt < 2; nt++)
        bw[nt] = *(const f16x8*)&AO[(size_t)(128 + (nt*16 + lr)*4 + lk)*AST + 32];
    #pragma unroll
    for (int nt = 0; nt < 2; nt++)
        #pragma unroll
        for (int mt = 0; mt < 4; mt++)
            d[nt*4+mt] = __builtin_amdgcn_mfma_f32_16x16x32_f16(a2[mt], bw[nt], zero, 0, 0, 0);

    // bias + gelu on D (fp32)
    #pragma unroll
    for (int nt = 0; nt < 2; nt++)
        #pragma unroll
        for (int mt = 0; mt < 4; mt++)
            #pragma unroll
            for (int r = 0; r < 4; r++)
                d[nt*4+mt][r] = gelu_f(d[nt*4+mt][r] + bias2[nt]);

    if (!LAST){
        // direct f16x4 store: lane owns 4 consecutive positions of channel nt*16+lr
        #pragma unroll
        for (int nt = 0; nt < 2; nt++)
            #pragma unroll
            for (int mt = 0; mt < 4; mt++){
                const f32x4 dv = d[nt*4+mt];
                f16x4 hv = { (f16_t)dv[0], (f16_t)dv[1], (f16_t)dv[2], (f16_t)dv[3] };
                *(f16x4*)&hout[base + (size_t)(nt*16 + lr)*L_
                               + l0 + wv*64 + mt*16 + lk*4] = hv;
            }
    } else {
        // channel sums: reduce over the 4 lk-lanes sharing lr, then global atomic.
        // No fence: the head_kernel launch boundary orders pooled visibility.
        #pragma unroll
        for (int nt = 0; nt < 2; nt++){
            float ps = 0.f;
            #pragma unroll
            for (int mt = 0; mt < 4; mt++)
                ps += d[nt*4+mt][0] + d[nt*4+mt][1] + d[nt*4+mt][2] + d[nt*4+mt][3];
            ps += __shfl_xor(ps, 16);
            ps += __shfl_xor(ps, 32);
            if (lk == 0) atomicAdd(&pooled[b*32 + nt*16 + lr], ps);
        }
    }
}

// ---- head: pooled/L -> Wh+bh -> BN(eval) -> gelu -> Wf+bf ----
__global__ __launch_bounds__(1024) void head_kernel(const float* __restrict__ pooled,
                                                    const float* __restrict__ Wh,
                                                    const float* __restrict__ bh,
                                                    const float* __restrict__ gam,
                                                    const float* __restrict__ bet,
                                                    const float* __restrict__ mean,
                                                    const float* __restrict__ var,
                                                    const float* __restrict__ Wf,
                                                    const float* __restrict__ bf,
                                                    float* __restrict__ out){
    __shared__ float y2[32][32];
    const int t = threadIdx.x;      // 0..1023
    const int b = t >> 5, c = t & 31;
    float a = bh[c];
    const float invL = 1.0f / (float)L_;
    #pragma unroll
    for (int d = 0; d < 32; d++) a += (pooled[b*32 + d] * invL) * Wh[d*32 + c];
    a = (a - mean[c]) * rsqrtf(var[c] + 1e-5f) * gam[c] + bet[c];
    y2[b][c] = gelu_f(a);
    __syncthreads();
    if (t < B_*DOUT_){
        const int b2 = t / DOUT_, j = t % DOUT_;
        float r = bf[j];
        #pragma unroll
        for (int c2 = 0; c2 < 32; c2++) r += y2[b2][c2] * Wf[c2*DOUT_ + j];
        out[t] = r;
    }
}

extern "C" void kernel_launch(void* const* d_in, const int* in_sizes, int n_in,
                              void* d_out, int out_size, void* d_ws, size_t ws_size,
                              hipStream_t stream){
    (void)in_sizes; (void)n_in; (void)out_size; (void)ws_size;
    const float* x    = (const float*)d_in[0];
    const float* fW1  = (const float*)d_in[1];
    const float* fb1  = (const float*)d_in[2];
    const float* fW2  = (const float*)d_in[3];
    const float* fb2  = (const float*)d_in[4];
    const float* Wh   = (const float*)d_in[5];
    const float* bh   = (const float*)d_in[6];
    const float* gam  = (const float*)d_in[7];
    const float* bet  = (const float*)d_in[8];
    const float* mean = (const float*)d_in[9];
    const float* var  = (const float*)d_in[10];
    const float* Wf   = (const float*)d_in[11];
    const float* bf   = (const float*)d_in[12];
    float* out = (float*)d_out;

    f16_t* hbuf   = (f16_t*)d_ws;                                  // B*C*L f16 (32 MB)
    float* part   = (float*)((char*)d_ws + (size_t)B_*C_*L_*2);    // B*H*S_*80 (~1.3 MB)
    float* pooled = part + (size_t)B_*H_*S_*80;                    // B*C

    dim3 sgrid(S_, H_, B_);
    dim3 bgrid(L_/TILE, B_);

    // 7 dispatches (x16 fused into stats0; pooled-zero fused into stats2;
    // head separate -- kernel boundary is the cheap ordering primitive).
    // stats0: reads x f32, writes part + x16 -> hbuf
    stats_kernel<float><<<sgrid, 256, 0, stream>>>(x, part, nullptr, hbuf);
    // block 0: in-place on hbuf f16
    block_kernel<false><<<bgrid, 256, 0, stream>>>(hbuf, hbuf, part,
        fW1, fb1, fW2, fb2, nullptr);
    // block 1 (in-place on hbuf f16)
    stats_kernel<f16_t><<<sgrid, 256, 0, stream>>>(hbuf, part, nullptr, nullptr);
    block_kernel<false><<<bgrid, 256, 0, stream>>>(hbuf, hbuf, part,
        fW1 + C_*C_, fb1 + C_, fW2 + C_*C_, fb2 + C_, nullptr);
    // block 2 (no h write; pooled reduce; stats2 zeroes pooled)
    stats_kernel<f16_t><<<sgrid, 256, 0, stream>>>(hbuf, part, pooled, nullptr);
    block_kernel<true><<<bgrid, 256, 0, stream>>>(hbuf, nullptr, part,
        fW1 + 2*C_*C_, fb1 + 2*C_, fW2 + 2*C_*C_, fb2 + 2*C_, pooled);

    head_kernel<<<1, 1024, 0, stream>>>(pooled, Wh, bh, gam, bet, mean, var, Wf, bf, out);
}

// Round 15
// 259.035 us; speedup vs baseline: 1.0777x; 1.0650x over previous
//
#include <hip/hip_runtime.h>
#include <cstddef>

#define B_ 32
#define C_ 32
#define L_ 16384
#define H_ 4
#define DH_ 8
#define NB_ 3
#define DOUT_ 10
#define SEG_ 512
#define S_ (L_/SEG_)   // 32 segments per (b,head)

#define TILE 512   // positions per WG, 512 threads (8 waves) -- parallel, not serial
#define AST  40    // A_lds row stride (halfs): 80 B/row; cols 32..39 = "holes" hold W1eff/W2

typedef _Float16 f16_t;
typedef _Float16 f16x2 __attribute__((ext_vector_type(2)));
typedef _Float16 f16x4 __attribute__((ext_vector_type(4)));
typedef _Float16 f16x8 __attribute__((ext_vector_type(8)));
typedef float    f32x4 __attribute__((ext_vector_type(4)));

// Branch-free gelu via Abramowitz-Stegun 7.1.25 erf approximation (|eps|<=2.5e-5,
// far below the f16 rounding the activation path already carries).
__device__ __forceinline__ float gelu_f(float x){
    const float z  = fabsf(x) * 0.70710678118654752440f;
    const float t  = __builtin_amdgcn_rcpf(fmaf(0.47047f, z, 1.0f));
    const float e  = __expf(-z * z);
    float p = fmaf(t, 0.7478556f, -0.0958798f);
    p = fmaf(t, p, 0.3480242f);
    const float erfz = 1.0f - p * t * e;          // erf(|x|/sqrt(2))
    const float phi  = fmaf(copysignf(erfz, x), 0.5f, 0.5f);
    return x * phi;
}

#define RED_MAX32(v) do{ v = fmaxf(v, __shfl_xor(v,1));  v = fmaxf(v, __shfl_xor(v,2)); \
                         v = fmaxf(v, __shfl_xor(v,4));  v = fmaxf(v, __shfl_xor(v,8)); \
                         v = fmaxf(v, __shfl_xor(v,16)); }while(0)
#define RED_SUM32(v) do{ v += __shfl_xor(v,1);  v += __shfl_xor(v,2); \
                         v += __shfl_xor(v,4);  v += __shfl_xor(v,8); \
                         v += __shfl_xor(v,16); }while(0)

// ---- stats: per (b, head, seg) partial max / sumexp / kv over a 512-pos segment ----
// f32 for x (layer 0), f16 for hbuf (layers 1,2 -- 32 MB, L3-resident).
// x16: layer 0 also emits the f16 conversion of x into hbuf while streaming.
// zpool: one WG zeroes pooled (replaces the memset launch).
template<typename T>
__global__ __launch_bounds__(256) void stats_kernel(const T* __restrict__ h,
                                                    float* __restrict__ part,
                                                    float* __restrict__ zpool,
                                                    f16_t* __restrict__ x16){
    const int seg = blockIdx.x;
    const int hd  = blockIdx.y;
    const int b   = blockIdx.z;
    const int t   = threadIdx.x;
    const int d   = t >> 5;   // 0..7  (feature within head); wave-half owns one d
    const int j   = t & 31;   // 0..31 (position lane)

    __shared__ float tile[8][SEG_];   // 16 KB
    __shared__ float sm[8];

    if (zpool != nullptr && blockIdx.x == 0 && blockIdx.y == 0 && blockIdx.z == 0)
        for (int i = t; i < B_*C_; i += 256) zpool[i] = 0.0f;

    const size_t boff = (size_t)b * ((size_t)C_*L_) + (size_t)(hd*DH_)*L_ + (size_t)seg*SEG_;
    const T* hb = h + boff;

    if constexpr (sizeof(T) == 4){
        f16_t* xb = (x16 != nullptr) ? (x16 + boff) : nullptr;
        for (int f = t; f < 8*SEG_/4; f += 256){
            const int row = f >> 7;
            const int c4  = (f & 127) << 2;
            const f32x4 v = *(const f32x4*)&hb[(size_t)row*L_ + c4];
            *(f32x4*)&tile[row][c4] = v;
            if (xb != nullptr){
                f16x4 hv = { (f16_t)v[0], (f16_t)v[1], (f16_t)v[2], (f16_t)v[3] };
                *(f16x4*)&xb[(size_t)row*L_ + c4] = hv;
            }
        }
    } else {
        for (int f = t; f < 8*SEG_/8; f += 256){
            const int row = f >> 6;            // 64 f16x8 chunks per row
            const int c8  = (f & 63) << 3;
            const f16x8 v = *(const f16x8*)&hb[(size_t)row*L_ + c8];
            f32x4 lo = {(float)v[0], (float)v[1], (float)v[2], (float)v[3]};
            f32x4 hi = {(float)v[4], (float)v[5], (float)v[6], (float)v[7]};
            *(f32x4*)&tile[row][c8]     = lo;
            *(f32x4*)&tile[row][c8 + 4] = hi;
        }
    }
    __syncthreads();

    float m = -INFINITY;
    #pragma unroll
    for (int i = 0; i < SEG_/32; i++) m = fmaxf(m, tile[d][j + 32*i]);
    RED_MAX32(m);
    if (j == 0) sm[d] = m;
    const float m_d = m;

    float s = 0.0f;
    float kv[8];
    #pragma unroll
    for (int e = 0; e < 8; e++) kv[e] = 0.0f;
    #pragma unroll
    for (int i = 0; i < SEG_/32; i++){
        const int k = j + 32*i;
        const float ek = __expf(tile[d][k] - m_d);
        s += ek;
        #pragma unroll
        for (int e = 0; e < 8; e++) kv[e] = fmaf(ek, tile[e][k], kv[e]);
    }
    RED_SUM32(s);
    #pragma unroll
    for (int e = 0; e < 8; e++){ RED_SUM32(kv[e]); }
    __syncthreads();

    float* po = part + (size_t)((b*H_ + hd)*S_ + seg) * 80;
    if (j == 0){
        po[8 + d] = s;
        #pragma unroll
        for (int e = 0; e < 8; e++) po[16 + d*8 + e] = kv[e];
    }
    if (t < 8) po[t] = sm[t];
}

// ---- per-position softmax P + FC1/FC2 via f16 MFMA ----
// R15: TILE=512 with 512 THREADS (8 waves/WG) -- parallel widening (NOT R5's
// serial 2-tile). Rationale: R12-R14 showed block time is latency-bound with
// inter-WG residency refusing to materialize (occ ~30% with all resource
// limits at 8 WG/CU). 8 waves inside one WG hide each other's latency through
// the single barrier -- intra-WG overlap is scheduler-guaranteed. WG count
// 1024 = exactly 4 WG/CU (one round); weight staging + merge amortized 2x.
// LDS 40960 B -> 4 WG/CU limit, matching the grid.
//  * REGISTER-DIRECT A-FRAGS, WEIGHTS IN AO HOLES (rows 0..255), SHUFFLE-
//    COMBINE MERGE (tid<256), ONE __syncthreads -- all as R10-R14.
//  * LAST: shfl + plain atomicAdd, NO fences (R11: device-scope fences = L2
//    writeback storm on non-coherent-XCD CDNA4, +130 us).
// OCCUPANCY ATTR (R12/R13/R14 ladder): (4,8) = no contraction-spill (VGPR 52)
// with lifted envelope; min>=5 contracts+spills; max=4 pins occupancy.
// MFMA layouts (m89/m91-verified): A-frag lane holds A[m=lane&15][k=(lane>>4)*8+j];
// B-frag B[k][n=lane&15]; C/D col=lane&15, row=(lane>>4)*4+reg.
template<bool LAST>
__global__ __launch_bounds__(512)
__attribute__((amdgpu_waves_per_eu(4, 8)))
void block_kernel(const f16_t* hin,
                  f16_t* hout,
                  const float* __restrict__ part,
                  const float* __restrict__ W1,
                  const float* __restrict__ b1,
                  const float* __restrict__ W2,
                  const float* __restrict__ b2,
                  float* __restrict__ pooled){
    __shared__ __align__(16) f16_t AO[TILE*AST];   // 40960 B total LDS

    const int tid  = threadIdx.x;
    const int b    = blockIdx.y;
    const int l0   = blockIdx.x * TILE;
    const size_t base = (size_t)b * ((size_t)C_*L_);

    const int wv   = tid >> 6;       // 0..7
    const int lane = tid & 63;
    const int lr   = lane & 15;
    const int lk   = lane >> 4;
    const int posb = l0 + wv*64 + lr;   // + mt*16

    // ---- prologue: h loads (reg-direct A layout), W2 -> holes, biases ----
    float h[4][8];
    #pragma unroll
    for (int j = 0; j < 8; j++)
        #pragma unroll
        for (int mt = 0; mt < 4; mt++)
            h[mt][j] = (float)hin[base + (size_t)(lk*8 + j)*L_ + posb + mt*16];

    // W2 -> hole-rows 128..255: W2[k*32+n] -> hole(n,k)
    for (int i = tid; i < 1024; i += 512){
        const int k = i >> 5, n = i & 31;
        AO[(size_t)(128 + n*4 + (k >> 3))*AST + 32 + (k & 7)] = (f16_t)W2[i];
    }
    float bias1[2], bias2[2];
    #pragma unroll
    for (int nt = 0; nt < 2; nt++){ bias1[nt] = b1[nt*16 + lr]; bias2[nt] = b2[nt*16 + lr]; }

    // ---- per-position softmax -> A-frags in registers (h dies here) ----
    f16x8 a[4];
    #pragma unroll
    for (int mt = 0; mt < 4; mt++){
        float mq = h[mt][0];
        #pragma unroll
        for (int j = 1; j < 8; j++) mq = fmaxf(mq, h[mt][j]);
        float es[8]; float qs = 0.f;
        #pragma unroll
        for (int j = 0; j < 8; j++){ es[j] = __expf(h[mt][j] - mq); qs += es[j]; }
        const float inv = __builtin_amdgcn_rcpf(qs);
        #pragma unroll
        for (int j = 0; j < 8; j++) a[mt][j] = (f16_t)(es[j] * inv);
    }

    // ---- merge (tid<256): 4 segments per lane + shfl logsumexp over 8 q-lanes ----
    if (tid < 256){
        const int row = tid >> 3;        // c_in 0..31
        const int qq  = tid & 7;         // segment group / n-column group
        const int hdm = row >> 3, dm = row & 7;
        const float* pp = part + (size_t)(b*H_ + hdm) * S_ * 80;
        float pm[4];
        #pragma unroll
        for (int t4 = 0; t4 < 4; t4++) pm[t4] = pp[(qq + 8*t4)*80 + dm];
        float M = fmaxf(fmaxf(pm[0], pm[1]), fmaxf(pm[2], pm[3]));
        float ss = 0.f;
        float kvr[8];
        #pragma unroll
        for (int e = 0; e < 8; e++) kvr[e] = 0.f;
        #pragma unroll
        for (int t4 = 0; t4 < 4; t4++){
            const int s = qq + 8*t4;
            const float sc = __expf(pm[t4] - M);
            ss = fmaf(pp[s*80 + 8 + dm], sc, ss);
            const f32x4 k0 = *(const f32x4*)&pp[s*80 + 16 + dm*8];
            const f32x4 k1 = *(const f32x4*)&pp[s*80 + 16 + dm*8 + 4];
            #pragma unroll
            for (int e = 0; e < 4; e++){
                kvr[e]   = fmaf(k0[e], sc, kvr[e]);
                kvr[4+e] = fmaf(k1[e], sc, kvr[4+e]);
            }
        }
        // combine across the 8 q-lanes (lane bits 0..2): logsumexp merge
        #pragma unroll
        for (int off = 1; off < 8; off <<= 1){
            const float Mo  = __shfl_xor(M, off);
            const float sso = __shfl_xor(ss, off);
            const float Mn  = fmaxf(M, Mo);
            const float sa  = __expf(M - Mn), sb = __expf(Mo - Mn);
            ss = ss*sa + sso*sb;
            #pragma unroll
            for (int e = 0; e < 8; e++){
                const float ko = __shfl_xor(kvr[e], off);
                kvr[e] = kvr[e]*sa + ko*sb;
            }
            M = Mn;
        }
        const float iss = 1.0f / ss;

        // W1eff[row][qq*4..+3] = sum_e kvn[row][e] * W1[hdm*8+e][qq*4..+3] -> holes 0..127
        f32x4 acc = {0.f, 0.f, 0.f, 0.f};
        #pragma unroll
        for (int e = 0; e < 8; e++){
            const f32x4 w = *(const f32x4*)&W1[(hdm*8 + e)*32 + qq*4];
            acc += kvr[e] * w;
        }
        #pragma unroll
        for (int j2 = 0; j2 < 4; j2++)
            AO[(size_t)((qq*4 + j2)*4 + hdm)*AST + 32 + dm] = (f16_t)(acc[j2] * iss);
    }
    __syncthreads();   // the ONLY barrier: W1eff + W2 holes visible

    // ---- MFMA FCs ----
    const f32x4 zero = {0.f, 0.f, 0.f, 0.f};
    f16x8 bw[2];
    f32x4 d[8];

    // FC1: A = P (registers), B = W1eff (holes 0..127)
    #pragma unroll
    for (int nt = 0; nt < 2; nt++)
        bw[nt] = *(const f16x8*)&AO[(size_t)((nt*16 + lr)*4 + lk)*AST + 32];
    #pragma unroll
    for (int nt = 0; nt < 2; nt++)
        #pragma unroll
        for (int mt = 0; mt < 4; mt++)
            d[nt*4+mt] = __builtin_amdgcn_mfma_f32_16x16x32_f16(a[mt], bw[nt], zero, 0, 0, 0);

    // bias + gelu + writeback as A2 into AO rows (cols 0..31; wave-private rows)
    #pragma unroll
    for (int nt = 0; nt < 2; nt++){
        #pragma unroll
        for (int mt = 0; mt < 4; mt++)
            #pragma unroll
            for (int r = 0; r < 4; r++){
                const float v = gelu_f(d[nt*4+mt][r] + bias1[nt]);
                AO[(size_t)(wv*64 + mt*16 + lk*4 + r)*AST + (nt*16 + lr)] = (f16_t)v;
            }
    }

    // FC2: A2 from AO rows, B = W2 (holes 128..255). Same-wave LDS write->read
    // ordering (R5-verified) -- no barrier.
    f16x8 a2[4];
    #pragma unroll
    for (int mt = 0; mt < 4; mt++)
        a2[mt] = *(const f16x8*)&AO[(size_t)(wv*64 + mt*16 + lr)*AST + lk*8];
    #pragma unroll
    for (int nt = 0; nt < 2; nt++)
        bw[nt] = *(const f16x8*)&AO[(size_t)(128 + (nt*16 + lr)*4 + lk)*AST + 32];
    #pragma unroll
    for (int nt = 0; nt < 2; nt++)
        #pragma unroll
        for (int mt = 0; mt < 4; mt++)
            d[nt*4+mt] = __builtin_amdgcn_mfma_f32_16x16x32_f16(a2[mt], bw[nt], zero, 0, 0, 0);

    // bias + gelu on D (fp32)
    #pragma unroll
    for (int nt = 0; nt < 2; nt++)
        #pragma unroll
        for (int mt = 0; mt < 4; mt++)
            #pragma unroll
            for (int r = 0; r < 4; r++)
                d[nt*4+mt][r] = gelu_f(d[nt*4+mt][r] + bias2[nt]);

    if (!LAST){
        // direct f16x4 store: lane owns 4 consecutive positions of channel nt*16+lr
        #pragma unroll
        for (int nt = 0; nt < 2; nt++)
            #pragma unroll
            for (int mt = 0; mt < 4; mt++){
                const f32x4 dv = d[nt*4+mt];
                f16x4 hv = { (f16_t)dv[0], (f16_t)dv[1], (f16_t)dv[2], (f16_t)dv[3] };
                *(f16x4*)&hout[base + (size_t)(nt*16 + lr)*L_
                               + l0 + wv*64 + mt*16 + lk*4] = hv;
            }
    } else {
        // channel sums: reduce over the 4 lk-lanes sharing lr, then global atomic.
        // No fence: the head_kernel launch boundary orders pooled visibility.
        #pragma unroll
        for (int nt = 0; nt < 2; nt++){
            float ps = 0.f;
            #pragma unroll
            for (int mt = 0; mt < 4; mt++)
                ps += d[nt*4+mt][0] + d[nt*4+mt][1] + d[nt*4+mt][2] + d[nt*4+mt][3];
            ps += __shfl_xor(ps, 16);
            ps += __shfl_xor(ps, 32);
            if (lk == 0) atomicAdd(&pooled[b*32 + nt*16 + lr], ps);
        }
    }
}

// ---- head: pooled/L -> Wh+bh -> BN(eval) -> gelu -> Wf+bf ----
__global__ __launch_bounds__(1024) void head_kernel(const float* __restrict__ pooled,
                                                    const float* __restrict__ Wh,
                                                    const float* __restrict__ bh,
                                                    const float* __restrict__ gam,
                                                    const float* __restrict__ bet,
                                                    const float* __restrict__ mean,
                                                    const float* __restrict__ var,
                                                    const float* __restrict__ Wf,
                                                    const float* __restrict__ bf,
                                                    float* __restrict__ out){
    __shared__ float y2[32][32];
    const int t = threadIdx.x;      // 0..1023
    const int b = t >> 5, c = t & 31;
    float a = bh[c];
    const float invL = 1.0f / (float)L_;
    #pragma unroll
    for (int d = 0; d < 32; d++) a += (pooled[b*32 + d] * invL) * Wh[d*32 + c];
    a = (a - mean[c]) * rsqrtf(var[c] + 1e-5f) * gam[c] + bet[c];
    y2[b][c] = gelu_f(a);
    __syncthreads();
    if (t < B_*DOUT_){
        const int b2 = t / DOUT_, j = t % DOUT_;
        float r = bf[j];
        #pragma unroll
        for (int c2 = 0; c2 < 32; c2++) r += y2[b2][c2] * Wf[c2*DOUT_ + j];
        out[t] = r;
    }
}

extern "C" void kernel_launch(void* const* d_in, const int* in_sizes, int n_in,
                              void* d_out, int out_size, void* d_ws, size_t ws_size,
                              hipStream_t stream){
    (void)in_sizes; (void)n_in; (void)out_size; (void)ws_size;
    const float* x    = (const float*)d_in[0];
    const float* fW1  = (const float*)d_in[1];
    const float* fb1  = (const float*)d_in[2];
    const float* fW2  = (const float*)d_in[3];
    const float* fb2  = (const float*)d_in[4];
    const float* Wh   = (const float*)d_in[5];
    const float* bh   = (const float*)d_in[6];
    const float* gam  = (const float*)d_in[7];
    const float* bet  = (const float*)d_in[8];
    const float* mean = (const float*)d_in[9];
    const float* var  = (const float*)d_in[10];
    const float* Wf   = (const float*)d_in[11];
    const float* bf   = (const float*)d_in[12];
    float* out = (float*)d_out;

    f16_t* hbuf   = (f16_t*)d_ws;                                  // B*C*L f16 (32 MB)
    float* part   = (float*)((char*)d_ws + (size_t)B_*C_*L_*2);    // B*H*S_*80 (~1.3 MB)
    float* pooled = part + (size_t)B_*H_*S_*80;                    // B*C

    dim3 sgrid(S_, H_, B_);
    dim3 bgrid(L_/TILE, B_);   // 32 x 32 = 1024 WGs of 512 threads

    // 7 dispatches (x16 fused into stats0; pooled-zero fused into stats2;
    // head separate -- kernel boundary is the cheap ordering primitive).
    // stats0: reads x f32, writes part + x16 -> hbuf
    stats_kernel<float><<<sgrid, 256, 0, stream>>>(x, part, nullptr, hbuf);
    // block 0: in-place on hbuf f16
    block_kernel<false><<<bgrid, 512, 0, stream>>>(hbuf, hbuf, part,
        fW1, fb1, fW2, fb2, nullptr);
    // block 1 (in-place on hbuf f16)
    stats_kernel<f16_t><<<sgrid, 256, 0, stream>>>(hbuf, part, nullptr, nullptr);
    block_kernel<false><<<bgrid, 512, 0, stream>>>(hbuf, hbuf, part,
        fW1 + C_*C_, fb1 + C_, fW2 + C_*C_, fb2 + C_, nullptr);
    // block 2 (no h write; pooled reduce; stats2 zeroes pooled)
    stats_kernel<f16_t><<<sgrid, 256, 0, stream>>>(hbuf, part, pooled, nullptr);
    block_kernel<true><<<bgrid, 512, 0, stream>>>(hbuf, nullptr, part,
        fW1 + 2*C_*C_, fb1 + 2*C_, fW2 + 2*C_*C_, fb2 + 2*C_, pooled);

    head_kernel<<<1, 1024, 0, stream>>>(pooled, Wh, bh, gam, bet, mean, var, Wf, bf, out);
}